// Round 14
// baseline (41.211 us; speedup 1.0000x reference)
//
#include <hip/hip_runtime.h>
#include <hip/hip_bf16.h>
#include <math.h>

#define BB 16
#define NN 256
#define LL 1024
#define DD 256

constexpr float LN_EPS = 1e-5f;
constexpr float NEG_SLOPE = 0.01f;

typedef __attribute__((ext_vector_type(8))) short short8;
typedef __attribute__((ext_vector_type(4))) float f32x4;
typedef __attribute__((ext_vector_type(4))) int i32x4;

static __device__ __forceinline__ unsigned cvtpk(float lo, float hi) {
  __hip_bfloat162 h = __float22bfloat162_rn(make_float2(lo, hi));
  union { __hip_bfloat162 h; unsigned u; } v; v.h = h;
  return v.u;
}
static __device__ __forceinline__ short8 pack8(float4 f0, float4 f1) {
  union { i32x4 i; short8 s; } v;
  v.i.x = cvtpk(f0.x, f0.y);
  v.i.y = cvtpk(f0.z, f0.w);
  v.i.z = cvtpk(f1.x, f1.y);
  v.i.w = cvtpk(f1.z, f1.w);
  return v.s;
}
static __device__ __forceinline__ unsigned short f2bf(float f) {
  union { float f; unsigned u; } v; v.f = f;
  unsigned r = v.u + 0x7FFFu + ((v.u >> 16) & 1u);
  return (unsigned short)(r >> 16);
}

// ---------------------------------------------------------------------------
// agemm (MFMA), e-split: block = (b, l-tile 64, e-half 128).
//   aT[b][e][l] = sum_d W_nb[e,d]*atom[b,l,d] + b_nb[e]  (bf16)
//   s2part[eh][b][l] = partial sum over this e-half (attn adds the halves)
//   blocks 0..15 side-job: v1 columns; block 0: c0.
// 512 blocks x 512 thr (8 waves) -> ~54 KB LDS -> 2 resident blocks/CU:
// one block's MFMA overlaps the other's staging/barrier drains.
// W_nb traffic unchanged vs e-full blocks (e-halves disjoint).
// Wave w: e rows [e_base + w*16, +16), all 64 l.
// XCD swizzle: all 32 blocks of batch b land on XCD b&7.
// ---------------------------------------------------------------------------
__global__ __launch_bounds__(512) void agemm_kernel(
    const float* __restrict__ atom, const float* __restrict__ W_nb,
    const float* __restrict__ b_nb, const float* __restrict__ W_mol,
    const float* __restrict__ b_mol, const float* __restrict__ align_w,
    const float* __restrict__ align_b, unsigned short* __restrict__ aT,
    float* __restrict__ s2part, float* __restrict__ v1c) {
  __shared__ char atile[64 * 256 * 2];      // 32 KB bf16, XOR-swizzled
  __shared__ unsigned short sAT[128 * 68];  // 17 KB
  __shared__ float vp[32][16];
  __shared__ float s2p[8][66];              // padded, conflict-free

  int t = threadIdx.x;
  int w = t >> 6, lane = t & 63;
  int i = blockIdx.x;
  int x = i & 7, k = i >> 3;          // k in 0..63
  int b = x + 8 * (k >> 5);           // 32 blocks per b, all on XCD b&7
  int j = k & 31;
  int l0 = (j & 15) * 64;
  int eh = j >> 4;                    // e-half 0/1
  int e_base = eh * 128;
  int lo16 = lane & 15, g = lane >> 4;

  // ---- stage atom tile -> LDS bf16 (swizzled) ----
  {
    int r = t >> 3, dseg = (t & 7) * 32;
    const float* src = atom + (size_t)(b * LL + l0 + r) * DD + dseg;
    #pragma unroll
    for (int q = 0; q < 4; ++q) {
      float4 f0 = *(const float4*)(src + q * 8);
      float4 f1 = *(const float4*)(src + q * 8 + 4);
      int byte = ((r * 256 + dseg + q * 8) * 2) ^ ((r & 7) << 4);
      *(short8*)(atile + byte) = pack8(f0, f1);
    }
  }

  // ---- side job: v1 columns (blocks 0..15), c0 (block 0) ----
  if (i < 16) {
    int d0 = i * 16;
    int dl = t & 15, eseg = t >> 4;
    float acc = 0.f;
    #pragma unroll
    for (int q = 0; q < 8; ++q) {
      int e = eseg * 8 + q;
      acc += align_w[e] * W_mol[e * DD + d0 + dl];
    }
    vp[eseg][dl] = acc;
    __syncthreads();
    if (t < 16) {
      float s = 0.f;
      #pragma unroll
      for (int q = 0; q < 32; ++q) s += vp[q][t];
      v1c[d0 + t] = s;
    }
    if (i == 0 && w == 1) {
      float s = b_mol[lane] * align_w[lane] +
                b_mol[lane + 64] * align_w[lane + 64] +
                b_mol[lane + 128] * align_w[lane + 128] +
                b_mol[lane + 192] * align_w[lane + 192];
      #pragma unroll
      for (int off = 32; off > 0; off >>= 1) s += __shfl_xor(s, off, 64);
      if (lane == 0) v1c[256] = s + align_b[0];
    }
  }
  __syncthreads();

  // ---- MFMA: wave w -> e rows [e_base + w*16, +16), all 64 l from LDS ----
  f32x4 acc[4];
  #pragma unroll
  for (int n = 0; n < 4; ++n) acc[n] = f32x4{0.f, 0.f, 0.f, 0.f};

  const float* Ap = W_nb + (size_t)(e_base + w * 16 + lo16) * DD + g * 8;

  #pragma unroll 4
  for (int kk = 0; kk < 8; ++kk) {
    float4 f0 = *(const float4*)(Ap + kk * 32);
    float4 f1 = *(const float4*)(Ap + kk * 32 + 4);
    short8 af = pack8(f0, f1);
    short8 bf[4];
    #pragma unroll
    for (int n = 0; n < 4; ++n) {
      int l = n * 16 + lo16;
      int byte = ((l * 256 + kk * 32 + g * 8) * 2) ^ ((l & 7) << 4);
      bf[n] = *(const short8*)(atile + byte);
    }
    #pragma unroll
    for (int n = 0; n < 4; ++n)
      acc[n] = __builtin_amdgcn_mfma_f32_16x16x32_bf16(af, bf[n], acc[n], 0, 0, 0);
  }

  // ---- epilogue: +bias -> sAT (bf16); s2 partials from registers ----
  {
    float4 bias = *(const float4*)&b_nb[e_base + w * 16 + g * 4];
    float4 w2r = *(const float4*)&align_w[DD + e_base + w * 16 + g * 4];
    float p[4] = {0.f, 0.f, 0.f, 0.f};
    #pragma unroll
    for (int n = 0; n < 4; ++n) {
      int l = n * 16 + lo16;
      #pragma unroll
      for (int jj = 0; jj < 4; ++jj) {
        float v = acc[n][jj] + ((const float*)&bias)[jj];
        sAT[(w * 16 + g * 4 + jj) * 68 + l] = f2bf(v);
        p[n] += ((const float*)&w2r)[jj] * v;
      }
    }
    #pragma unroll
    for (int n = 0; n < 4; ++n) {
      p[n] += __shfl_xor(p[n], 16, 64);
      p[n] += __shfl_xor(p[n], 32, 64);
    }
    if (g == 0) {
      #pragma unroll
      for (int n = 0; n < 4; ++n) s2p[w][n * 16 + lo16] = p[n];
    }
  }
  __syncthreads();

  // ---- s2 partial sum over 8 waves (conflict-free) + store ----
  if (t < 64) {
    float s = 0.f;
    #pragma unroll
    for (int q = 0; q < 8; ++q) s += s2p[q][t];
    s2part[eh * BB * LL + b * LL + l0 + t] = s;
  }
  // ---- coalesced store to aT ----
  unsigned short* dst = aT + (size_t)b * DD * LL + (size_t)e_base * LL + l0;
  #pragma unroll
  for (int idx = t; idx < 2048; idx += 512) {
    int e = idx >> 4, ch = idx & 15;
    ushort4 v = *(const ushort4*)&sAT[e * 68 + ch * 4];
    *(ushort4*)(dst + (size_t)e * LL + ch * 4) = v;
  }
}

// ---------------------------------------------------------------------------
// attn: block = (b, 16 n-rows), 512 thr = 8 waves. XCD swizzle (b&7).
// R13 version; s2 = sum of the two e-half partials.
// ---------------------------------------------------------------------------
__global__ __launch_bounds__(512) void attn_kernel(
    const unsigned short* __restrict__ aT, const float* __restrict__ mol,
    const float* __restrict__ v1c, const float* __restrict__ s2part,
    const float* __restrict__ amask, const float* __restrict__ smask,
    const float* __restrict__ gamma, const float* __restrict__ beta,
    float* __restrict__ out) {
  __shared__ unsigned short sattn[16 * 1024];  // 32 KB, XOR-swizzled
  __shared__ float ctxp[2][16][260];           // padded rows
  __shared__ float v1s[256];
  __shared__ float s1s[16];
  __shared__ float mu_s[16], rs_s[16];
  int i = blockIdx.x;
  int x = i & 7, k = i >> 3;
  int b = x + 8 * (k >> 4);
  int n0 = (k & 15) * 16;
  int t = threadIdx.x, w = t >> 6, lane = t & 63;

  float c0 = v1c[256];
  if (t < 256) v1s[t] = v1c[t];
  __syncthreads();

  // ---- s1: 32 thr/row ----
  {
    int r = t >> 5, off = (t & 31) * 8;
    const float* mr = mol + (size_t)(b * NN + n0 + r) * DD + off;
    float s = 0.f;
    #pragma unroll
    for (int q = 0; q < 2; ++q) {
      float4 f = *(const float4*)(mr + q * 4);
      s += f.x * v1s[off + q * 4] + f.y * v1s[off + q * 4 + 1] +
           f.z * v1s[off + q * 4 + 2] + f.w * v1s[off + q * 4 + 3];
    }
    s += __shfl_xor(s, 1, 64);
    s += __shfl_xor(s, 2, 64);
    s += __shfl_xor(s, 4, 64);
    s += __shfl_xor(s, 8, 64);
    s += __shfl_xor(s, 16, 64);
    if ((t & 31) == 0) s1s[r] = s + c0;
  }
  __syncthreads();

  // ---- softmax: wave w -> rows 2w, 2w+1 ----
  {
    float s2v[16], amv[16], smv[16];
    #pragma unroll
    for (int q = 0; q < 16; ++q) {
      int l = lane + 64 * q;
      s2v[q] = s2part[b * LL + l] + s2part[BB * LL + b * LL + l];
      amv[q] = amask[b * LL + l];
      smv[q] = smask[b * LL + l];
    }
    #pragma unroll
    for (int rr = 0; rr < 2; ++rr) {
      int r = w * 2 + rr;
      float s1v = s1s[r];
      float p[16];
      float mx = -INFINITY;
      #pragma unroll
      for (int q = 0; q < 16; ++q) {
        float sc = s1v + s2v[q];
        sc = sc > 0.f ? sc : NEG_SLOPE * sc;
        sc += smv[q];
        p[q] = sc;
        mx = fmaxf(mx, sc);
      }
      #pragma unroll
      for (int off = 32; off > 0; off >>= 1) mx = fmaxf(mx, __shfl_xor(mx, off, 64));
      float sum = 0.f;
      #pragma unroll
      for (int q = 0; q < 16; ++q) {
        p[q] = __expf(p[q] - mx);
        sum += p[q];
      }
      #pragma unroll
      for (int off = 32; off > 0; off >>= 1) sum += __shfl_xor(sum, off, 64);
      float inv = 1.f / sum;
      #pragma unroll
      for (int q = 0; q < 16; ++q) {
        unsigned short bv = f2bf(p[q] * amv[q] * inv);
        int l = lane + 64 * q;
        int byte = ((r * 1024 + l) * 2) ^ ((r & 7) << 4);
        *(unsigned short*)((char*)sattn + byte) = bv;
      }
    }
  }
  __syncthreads();

  // ---- PV MFMA: wave = e-quadrant (w&3) x l-half (w>>2) ----
  int lo16 = lane & 15, g = lane >> 4;
  {
    int e0 = (w & 3) * 64, lh = w >> 2;
    f32x4 acc[4];
    #pragma unroll
    for (int n = 0; n < 4; ++n) acc[n] = f32x4{0.f, 0.f, 0.f, 0.f};
    const unsigned short* Bp =
        aT + (size_t)b * DD * LL + (size_t)(e0 + lo16) * LL + lh * 512 + g * 8;
    #pragma unroll 8
    for (int kk = 0; kk < 16; ++kk) {
      short8 afr = *(const short8*)((const char*)sattn +
          (((lo16 * 1024 + lh * 512 + kk * 32 + g * 8) * 2) ^ ((lo16 & 7) << 4)));
      #pragma unroll
      for (int n = 0; n < 4; ++n) {
        short8 bfr = *(const short8*)(Bp + (size_t)n * 16 * LL + kk * 32);
        acc[n] = __builtin_amdgcn_mfma_f32_16x16x32_bf16(afr, bfr, acc[n], 0, 0, 0);
      }
    }
    #pragma unroll
    for (int n = 0; n < 4; ++n)
      #pragma unroll
      for (int jj = 0; jj < 4; ++jj)
        ctxp[lh][g * 4 + jj][e0 + n * 16 + lo16] = acc[n][jj];
  }
  __syncthreads();

  // ---- LN stats: wave w -> rows 2w, 2w+1 ----
  #pragma unroll
  for (int rr = 0; rr < 2; ++rr) {
    int r = w * 2 + rr;
    float s = 0.f, sq = 0.f;
    #pragma unroll
    for (int jj = 0; jj < 4; ++jj) {
      int cc = lane + 64 * jj;
      float v = ctxp[0][r][cc] + ctxp[1][r][cc];
      s += v;
      sq += v * v;
    }
    #pragma unroll
    for (int off = 32; off > 0; off >>= 1) {
      s += __shfl_xor(s, off, 64);
      sq += __shfl_xor(sq, off, 64);
    }
    if (lane == 0) {
      float mu = s * (1.f / 256.f);
      float var = sq * (1.f / 256.f) - mu * mu;
      mu_s[r] = mu;
      rs_s[r] = rsqrtf(var + LN_EPS);
    }
  }
  __syncthreads();

  // ---- store ----
  #pragma unroll
  for (int q = 0; q < 8; ++q) {
    int idx = t + 512 * q;
    int r = idx >> 8, d = idx & 255;
    float v = ctxp[0][r][d] + ctxp[1][r][d];
    out[(size_t)(b * NN + n0 + r) * DD + d] =
        (v - mu_s[r]) * rs_s[r] * gamma[d] + beta[d];
  }
}

// ---------------------------------------------------------------------------
extern "C" void kernel_launch(void* const* d_in, const int* in_sizes, int n_in,
                              void* d_out, int out_size, void* d_ws, size_t ws_size,
                              hipStream_t stream) {
  const float* mol     = (const float*)d_in[0];
  const float* atom    = (const float*)d_in[1];
  const float* amask   = (const float*)d_in[2];
  const float* smask   = (const float*)d_in[3];
  const float* W_mol   = (const float*)d_in[4];
  const float* b_mol   = (const float*)d_in[5];
  const float* W_nb    = (const float*)d_in[6];
  const float* b_nb    = (const float*)d_in[7];
  const float* align_w = (const float*)d_in[8];
  const float* align_b = (const float*)d_in[9];
  const float* gamma   = (const float*)d_in[10];
  const float* beta    = (const float*)d_in[11];
  float* outp = (float*)d_out;

  char* wsb = (char*)d_ws;
  unsigned short* aT = (unsigned short*)wsb;          // 8 MB
  float* s2part = (float*)(wsb + 8388608);            // 2*16*1024 f = 128 KB
  float* v1c = s2part + 2 * BB * LL;                  // 257 floats

  agemm_kernel<<<512, 512, 0, stream>>>(atom, W_nb, b_nb, W_mol, b_mol,
                                        align_w, align_b, aT, s2part, v1c);
  attn_kernel<<<256, 512, 0, stream>>>(aT, mol, v1c, s2part, amask, smask,
                                       gamma, beta, outp);
}